// Round 4
// baseline (21155.896 us; speedup 1.0000x reference)
//
#include <hip/hip_runtime.h>
#include <math.h>

#define TT 512
#define BB 256
#define EE 300
#define KK 9
#define HH 256
#define GG 1024
#define CHS 64
#define NCH (TT/CHS)

// workspace layout (floats)
#define XG_GRP ((size_t)CHS*32*GG)                  // 2,097,152 per group
#define OFF_XG  ((size_t)0)                         // 16 groups
#define OFF_HR  (OFF_XG + (size_t)16*XG_GRP)        // h ring: 16 grp * 2 par * 32 b * 256
#define OFF_EF  (OFF_HR + (size_t)16*2*32*HH)
#define OFF_EB  (OFF_EF + (size_t)BB*TT*KK)
#define OFF_ND  (OFF_EB + (size_t)BB*TT*KK)
#define OFF_BAR (OFF_ND + 256)                      // 16 counters, 32-uint stride

// ---- 16-block group barrier: private cacheline counter, monotonic target ----
__device__ __forceinline__ void gbar(unsigned* c, unsigned target) {
  __syncthreads();
  if (threadIdx.x == 0) {
    __threadfence();
    __hip_atomic_fetch_add(c, 1u, __ATOMIC_ACQ_REL, __HIP_MEMORY_SCOPE_AGENT);
    while (__hip_atomic_load(c, __ATOMIC_ACQUIRE, __HIP_MEMORY_SCOPE_AGENT) < target)
      __builtin_amdgcn_s_sleep(2);
    __threadfence();
  }
  __syncthreads();
}

union SMem {
  struct { float As[60][132]; float Ws[60][132]; } xg;
  struct { float HT[32][260]; float P[4][64][33]; } st;
};

__global__ __launch_bounds__(256, 1) void lstm_fused(
    const int* __restrict__ ids, const int* __restrict__ lens,
    const float* __restrict__ emb,
    const float* __restrict__ W_ih_f, const float* __restrict__ W_hh_f, const float* __restrict__ b_f,
    const float* __restrict__ W_ih_b, const float* __restrict__ W_hh_b, const float* __restrict__ b_b,
    const float* __restrict__ W_out, const float* __restrict__ b_out,
    float* __restrict__ ws)
{
  __shared__ SMem sm;
  __shared__ float Wk[260];
  __shared__ int tokid[128];

  const int tid = threadIdx.x;
  const int jt  = blockIdx.x >> 4;     // 0..15 (j-tile / xg row-slab)
  const int g   = blockIdx.x & 15;     // group: 16 blocks stride-16 apart (same XCD)
  const int dir = g >> 3;
  const int bt  = g & 7;
  const int b0  = bt * 32;

  const float* W_ih = dir ? W_ih_b : W_ih_f;
  const float* W_hh = dir ? W_hh_b : W_hh_f;
  const float* bias = dir ? b_b : b_f;

  float* xgg  = ws + OFF_XG + (size_t)g * XG_GRP;
  float* hrg  = ws + OFF_HR + (size_t)g * (2*32*HH);
  float* emis = ws + (dir ? OFF_EB : OFF_EF);
  unsigned* bar = (unsigned*)(ws + OFF_BAR) + g * 32;

  // gate-thread ownership (fixed for whole kernel): batch eb, j-cols jj and jj+8
  const int eb = tid & 31;
  const int jj = tid >> 5;
  const int len_e = lens[b0 + eb];
  float c_e[2] = {0.f, 0.f};

  // GEMM ownership: wave wseg = k-slice of 64; lane rrow = gate-row
  const int wseg = __builtin_amdgcn_readfirstlane(tid >> 6);
  const int rrow = tid & 63;
  const int grow = (rrow >> 4) * 256 + jt * 16 + (rrow & 15);

  float bo = (jt < KK && dir == 0) ? b_out[jt] : 0.f;
  unsigned barcnt = 0;

  for (int ci = 0; ci < NCH; ++ci) {
    // ======== xg phase: group-local. Block computes token-rows [jt*128, +128) ========
    __syncthreads();   // LDS reuse guard (st -> xg)
    if (tid < 128) {
      int m = jt * 128 + tid;                 // m = sl*32 + bl
      int sidx = ci * CHS + (m >> 5);
      int t = dir ? (TT - 1 - sidx) : sidx;
      tokid[tid] = ids[t * BB + b0 + (m & 31)];
    }
    {
      const int ty = tid >> 4, tx = tid & 15;
      for (int nt = 0; nt < 8; ++nt) {
        float acc[8][8];
        #pragma unroll
        for (int a_ = 0; a_ < 8; ++a_)
          #pragma unroll
          for (int b_ = 0; b_ < 8; ++b_) acc[a_][b_] = 0.f;

        for (int kc = 0; kc < 5; ++kc) {
          __syncthreads();
          for (int i = tid; i < 128 * 15; i += 256) {
            int mm = i / 15, kq = i - mm * 15;
            float4 v = *(const float4*)&emb[(size_t)tokid[mm] * EE + kc * 60 + kq * 4];
            sm.xg.As[kq*4+0][mm] = v.x; sm.xg.As[kq*4+1][mm] = v.y;
            sm.xg.As[kq*4+2][mm] = v.z; sm.xg.As[kq*4+3][mm] = v.w;
          }
          for (int i = tid; i < 128 * 15; i += 256) {
            int nn = i / 15, kq = i - nn * 15;
            float4 v = *(const float4*)&W_ih[(size_t)(nt*128+nn) * EE + kc * 60 + kq * 4];
            sm.xg.Ws[kq*4+0][nn] = v.x; sm.xg.Ws[kq*4+1][nn] = v.y;
            sm.xg.Ws[kq*4+2][nn] = v.z; sm.xg.Ws[kq*4+3][nn] = v.w;
          }
          __syncthreads();
          for (int kk = 0; kk < 60; ++kk) {
            float4 a0 = *(const float4*)&sm.xg.As[kk][ty*8];
            float4 a1 = *(const float4*)&sm.xg.As[kk][ty*8+4];
            float4 w0 = *(const float4*)&sm.xg.Ws[kk][tx*8];
            float4 w1 = *(const float4*)&sm.xg.Ws[kk][tx*8+4];
            float av[8] = {a0.x,a0.y,a0.z,a0.w,a1.x,a1.y,a1.z,a1.w};
            float wv8[8] = {w0.x,w0.y,w0.z,w0.w,w1.x,w1.y,w1.z,w1.w};
            #pragma unroll
            for (int im = 0; im < 8; ++im)
              #pragma unroll
              for (int in = 0; in < 8; ++in) acc[im][in] += av[im] * wv8[in];
          }
        }
        #pragma unroll
        for (int im = 0; im < 8; ++im) {
          int m = ty*8 + im;
          int n = nt*128 + tx*8;
          float4 o0, o1;
          o0.x = acc[im][0] + bias[n+0]; o0.y = acc[im][1] + bias[n+1];
          o0.z = acc[im][2] + bias[n+2]; o0.w = acc[im][3] + bias[n+3];
          o1.x = acc[im][4] + bias[n+4]; o1.y = acc[im][5] + bias[n+5];
          o1.z = acc[im][6] + bias[n+6]; o1.w = acc[im][7] + bias[n+7];
          float* dst = &xgg[(size_t)(jt*128 + m) * GG + n];
          *(float4*)dst = o0; *(float4*)(dst+4) = o1;
        }
      }
    }

    // W_hh slice into VGPRs (once per chunk); W_out row into LDS
    float4 wv[16];
    #pragma unroll
    for (int i = 0; i < 16; ++i)
      wv[i] = *(const float4*)&W_hh[(size_t)grow * HH + wseg*64 + i*4];
    if (jt < KK && tid < 64)
      *(float4*)&Wk[tid*4] = *(const float4*)&W_out[(size_t)jt*512 + dir*256 + tid*4];

    gbar(bar, (++barcnt) * 16);   // group xg complete & visible

    // ======== 64 recurrent steps ========
    for (int sl = 0; sl < CHS; ++sl) {
      const int s = ci * CHS + sl;
      const int t = dir ? (TT - 1 - s) : s;
      const int first = (s == 0);
      const float* hprev = hrg + (size_t)(s & 1) * (32*HH);
      float*       hout  = hrg + (size_t)((s & 1) ^ 1) * (32*HH);

      // stage h_prev (group-local, coalesced)
      if (!first) {
        for (int i = tid; i < 2048; i += 256) {
          int bl = i >> 6, k4 = i & 63;
          *(float4*)&sm.st.HT[bl][k4*4] = *(const float4*)&hprev[bl*HH + k4*4];
        }
      }
      __syncthreads();

      // GEMM partials: P[wseg][rrow][b] = W[grow, kslice] . h[b, kslice]
      if (!first) {
        #pragma unroll 2
        for (int b = 0; b < 32; ++b) {
          const float* hb = &sm.st.HT[b][wseg*64];   // wave-uniform -> broadcast
          float a0 = 0.f, a1 = 0.f, a2 = 0.f, a3 = 0.f;
          #pragma unroll
          for (int i = 0; i < 16; ++i) {
            float4 h4 = *(const float4*)&hb[i*4];
            a0 += wv[i].x * h4.x; a1 += wv[i].y * h4.y;
            a2 += wv[i].z * h4.z; a3 += wv[i].w * h4.w;
          }
          sm.st.P[wseg][rrow][b] = (a0 + a1) + (a2 + a3);
        }
      }
      __syncthreads();

      // combine + gates + state update
      {
        const bool m = t < len_e;
        const float* xrow = xgg + (size_t)(sl*32 + eb) * GG + jt*16;
        #pragma unroll
        for (int h2 = 0; h2 < 2; ++h2) {
          const int jl = jj + h2*8;
          float gt[4];
          #pragma unroll
          for (int q = 0; q < 4; ++q) {
            float v = xrow[q*256 + jl];
            if (!first)
              v += sm.st.P[0][q*16+jl][eb] + sm.st.P[1][q*16+jl][eb]
                 + sm.st.P[2][q*16+jl][eb] + sm.st.P[3][q*16+jl][eb];
            gt[q] = v;
          }
          float si = 1.f / (1.f + expf(-gt[0]));
          float sf = 1.f / (1.f + expf(-gt[1]));
          float so = 1.f / (1.f + expf(-gt[3]));
          float c_old = first ? 0.f : c_e[h2];
          float h_old = first ? 0.f : sm.st.HT[eb][jt*16 + jl];
          float cn = sf * c_old + si * tanhf(gt[2]);
          float hn = so * tanhf(cn);
          float ho = m ? hn : h_old;
          float co = m ? cn : c_old;
          c_e[h2] = co;
          hout[eb * HH + jt*16 + jl] = ho;
        }
      }

      // fused emission for previous timestep (jt<9; h_prev still staged)
      if (jt < KK && !first) {
        const int ebb = tid >> 3, seg = tid & 7;
        float r = 0.f;
        #pragma unroll
        for (int u = 0; u < 8; ++u) {
          int c = (u*8 + seg) * 4;
          float4 h4 = *(const float4*)&sm.st.HT[ebb][c];
          float4 w4 = *(const float4*)&Wk[c];
          r += h4.x*w4.x + h4.y*w4.y + h4.z*w4.z + h4.w*w4.w;
        }
        r += __shfl_down(r, 4); r += __shfl_down(r, 2); r += __shfl_down(r, 1);
        if (seg == 0) {
          int tprev = dir ? t + 1 : t - 1;
          emis[((size_t)(b0 + ebb) * TT + tprev) * KK + jt] = r + bo;
        }
      }

      gbar(bar, (++barcnt) * 16);
    }
  }

  // ======== final emission: last processed timestep (h at parity 0) ========
  if (jt < KK) {
    const float* hlast = hrg;   // parity (511&1)^1 == 0
    for (int i = tid; i < 2048; i += 256) {
      int bl = i >> 6, k4 = i & 63;
      *(float4*)&sm.st.HT[bl][k4*4] = *(const float4*)&hlast[bl*HH + k4*4];
    }
    __syncthreads();
    const int ebb = tid >> 3, seg = tid & 7;
    float r = 0.f;
    #pragma unroll
    for (int u = 0; u < 8; ++u) {
      int c = (u*8 + seg) * 4;
      float4 h4 = *(const float4*)&sm.st.HT[ebb][c];
      float4 w4 = *(const float4*)&Wk[c];
      r += h4.x*w4.x + h4.y*w4.y + h4.z*w4.z + h4.w*w4.w;
    }
    r += __shfl_down(r, 4); r += __shfl_down(r, 2); r += __shfl_down(r, 1);
    if (seg == 0) {
      int tlast = dir ? 0 : TT - 1;
      emis[((size_t)(b0 + ebb) * TT + tlast) * KK + jt] = r + bo;
    }
  }
}

// ---------------- CRF (identical numerics to rounds 1-3) ----------------
__global__ __launch_bounds__(64) void crf_kernel(
    const float* __restrict__ emis_f, const float* __restrict__ emis_b2,
    const int* __restrict__ labels, const int* __restrict__ lens,
    const float* __restrict__ start_trans, const float* __restrict__ end_trans,
    const float* __restrict__ trans,
    float* __restrict__ numden, float* __restrict__ outp)
{
  const int b = blockIdx.x;
  const int lane = threadIdx.x;
  __shared__ __align__(16) float em[TT * KK];
  __shared__ unsigned char hist[TT * KK];
  const float4* ef = (const float4*)(emis_f + (size_t)b * TT * KK);
  const float4* eb = (const float4*)(emis_b2 + (size_t)b * TT * KK);
  for (int i = lane; i < TT*KK/4; i += 64) {
    float4 a = ef[i], c = eb[i];
    float4 o; o.x = a.x+c.x; o.y = a.y+c.y; o.z = a.z+c.z; o.w = a.w+c.w;
    ((float4*)em)[i] = o;
  }
  const int len = lens[b];
  const int k = lane < KK ? lane : KK-1;
  float tc[KK];
  #pragma unroll
  for (int jj = 0; jj < KK; ++jj) tc[jj] = trans[jj*KK + k];
  __syncthreads();

  float nacc = 0.f;
  for (int t = lane; t < TT; t += 64) {
    int lt = labels[t*BB + b];
    if (t == 0) nacc += start_trans[lt] + em[lt];
    else if (t < len) nacc += trans[labels[(t-1)*BB + b]*KK + lt] + em[t*KK + lt];
  }
  if (lane == 0) nacc += end_trans[labels[(size_t)(len-1)*BB + b]];
  #pragma unroll
  for (int off = 32; off; off >>= 1) nacc += __shfl_down(nacc, off);

  float alpha[KK], score[KK];
  #pragma unroll
  for (int jj = 0; jj < KK; ++jj) {
    float v = start_trans[jj] + em[jj];
    alpha[jj] = v; score[jj] = v;
  }
  for (int t = 1; t < TT; ++t) {
    float av[KK]; float mx = -1e30f;
    #pragma unroll
    for (int jj = 0; jj < KK; ++jj) { av[jj] = alpha[jj] + tc[jj]; mx = fmaxf(mx, av[jj]); }
    float ssum = 0.f;
    #pragma unroll
    for (int jj = 0; jj < KK; ++jj) ssum += expf(av[jj] - mx);
    float e_tk = em[t*KK + k];
    float na = mx + logf(ssum) + e_tk;
    float best = -1e30f; int bj = 0;
    #pragma unroll
    for (int jj = 0; jj < KK; ++jj) {
      float sv = score[jj] + tc[jj];
      if (sv > best) { best = sv; bj = jj; }
    }
    float ns = best + e_tk;
    bool msk = t < len;
    na = msk ? na : alpha[k];
    ns = msk ? ns : score[k];
    if (lane < KK) hist[(t-1)*KK + lane] = (unsigned char)bj;
    #pragma unroll
    for (int jj = 0; jj < KK; ++jj) { alpha[jj] = __shfl(na, jj); score[jj] = __shfl(ns, jj); }
  }
  float dm = -1e30f;
  #pragma unroll
  for (int jj = 0; jj < KK; ++jj) dm = fmaxf(dm, alpha[jj] + end_trans[jj]);
  float dsum = 0.f;
  #pragma unroll
  for (int jj = 0; jj < KK; ++jj) dsum += expf(alpha[jj] + end_trans[jj] - dm);
  float denom = dm + logf(dsum);
  int bl_ = 0; float bs = -1e30f;
  #pragma unroll
  for (int jj = 0; jj < KK; ++jj) {
    float v = score[jj] + end_trans[jj];
    if (v > bs) { bs = v; bl_ = jj; }
  }
  if (lane == 0) numden[b] = nacc - denom;
  __syncthreads();
  if (lane == 0) {
    int tag = bl_;
    outp[1 + (size_t)(TT-1)*BB + b] = ((TT-1) < len) ? (float)bl_ : 0.f;
    for (int s = TT-2; s >= 0; --s) {
      tag = ((s+1) < len) ? (int)hist[s*KK + tag] : bl_;
      outp[1 + (size_t)s*BB + b] = (s < len) ? (float)tag : 0.f;
    }
  }
}

__global__ __launch_bounds__(256) void loss_reduce_kernel(
    const float* __restrict__ numden, float* __restrict__ out)
{
  __shared__ float sh[256];
  int tid = threadIdx.x;
  sh[tid] = numden[tid];
  __syncthreads();
  for (int s = 128; s > 0; s >>= 1) {
    if (tid < s) sh[tid] += sh[tid + s];
    __syncthreads();
  }
  if (tid == 0) out[0] = -sh[0];
}

extern "C" void kernel_launch(void* const* d_in, const int* in_sizes, int n_in,
                              void* d_out, int out_size, void* d_ws, size_t ws_size,
                              hipStream_t stream)
{
  const int*   ids    = (const int*)d_in[0];
  const int*   lens   = (const int*)d_in[1];
  const int*   labels = (const int*)d_in[2];
  const float* emb    = (const float*)d_in[3];
  const float* W_ih_f = (const float*)d_in[4];
  const float* W_hh_f = (const float*)d_in[5];
  const float* b_f    = (const float*)d_in[6];
  const float* W_ih_b = (const float*)d_in[7];
  const float* W_hh_b = (const float*)d_in[8];
  const float* b_b    = (const float*)d_in[9];
  const float* W_out  = (const float*)d_in[10];
  const float* b_out  = (const float*)d_in[11];
  const float* s_tr   = (const float*)d_in[12];
  const float* e_tr   = (const float*)d_in[13];
  const float* trans  = (const float*)d_in[14];
  float* out = (float*)d_out;

  float* ws = (float*)d_ws;
  float* emis_f = ws + OFF_EF;
  float* emis_b = ws + OFF_EB;
  float* numden = ws + OFF_ND;

  // zero the group-barrier counters (monotonic targets need 0 start each call)
  hipMemsetAsync((char*)d_ws + OFF_BAR * sizeof(float), 0, 16 * 32 * sizeof(unsigned), stream);

  lstm_fused<<<256, 256, 0, stream>>>(ids, lens, emb,
      W_ih_f, W_hh_f, b_f, W_ih_b, W_hh_b, b_b, W_out, b_out, ws);

  crf_kernel<<<BB, 64, 0, stream>>>(emis_f, emis_b, labels, lens, s_tr, e_tr, trans, numden, out);
  loss_reduce_kernel<<<1, 256, 0, stream>>>(numden, out);
}

// Round 5
// 9789.439 us; speedup vs baseline: 2.1611x; 2.1611x over previous
//
#include <hip/hip_runtime.h>
#include <math.h>

#define TT 512
#define BB 256
#define EE 300
#define KK 9
#define HH 256
#define GG 1024
#define CHS 64
#define NCH (TT/CHS)

// ws offsets (floats)
#define OFF_XG ((size_t)0)                          // 2*CHS*BB*GG
#define OFF_WT (OFF_XG + (size_t)2*CHS*BB*GG)       // 2*64*1024 float4
#define OFF_HS (OFF_WT + (size_t)2*64*1024*4)
#define OFF_CS (OFF_HS + (size_t)2*BB*HH)
#define OFF_EF (OFF_CS + (size_t)2*BB*HH)
#define OFF_EB (OFF_EF + (size_t)BB*TT*KK)
#define OFF_ND (OFF_EB + (size_t)BB*TT*KK)

// ---------------- W_hh transpose/pack: Wt[dir][k4][row] = W[row][4k4..4k4+3] ----------------
__global__ __launch_bounds__(1024) void wtrans_kernel(
    const float* __restrict__ Wf, const float* __restrict__ Wb, float* __restrict__ Wt)
{
  int idx = blockIdx.x * 1024 + threadIdx.x;   // 131072 = 2 * 1024 * 64
  int dir = idx >> 16;
  int r   = (idx >> 6) & 1023;
  int k4  = idx & 63;
  const float* W = dir ? Wb : Wf;
  float4 v = *(const float4*)&W[(size_t)r * HH + k4 * 4];   // coalesced read (lanes = k4)
  ((float4*)Wt)[(size_t)dir * 65536 + (size_t)k4 * 1024 + r] = v;
}

// ---------------- xg chunk GEMM: both dirs, 256 blocks x 128 tokens x 1024 gates ----------------
__global__ __launch_bounds__(256) void gemm_xg_kernel(
    const int* __restrict__ ids, const float* __restrict__ emb,
    const float* __restrict__ W_ih_f, const float* __restrict__ W_ih_b,
    const float* __restrict__ b_f, const float* __restrict__ b_b,
    float* __restrict__ xgc, int ci)
{
  __shared__ float As[60][132];
  __shared__ float Ws[60][132];
  __shared__ int tokid[128];
  const int tid = threadIdx.x;
  const int dir = blockIdx.x >> 7;
  const int r   = blockIdx.x & 127;
  const float* W_ih = dir ? W_ih_b : W_ih_f;
  const float* bias = dir ? b_b : b_f;

  if (tid < 128) {
    int m = r * 128 + tid;               // chunk-local token row (sl*256 + bl)
    int sidx = ci * CHS + (m >> 8);
    int t = dir ? (TT - 1 - sidx) : sidx;
    tokid[tid] = ids[t * BB + (m & 255)];
  }
  __syncthreads();

  const int ty = tid >> 4, tx = tid & 15;
  for (int nt = 0; nt < 8; ++nt) {
    float acc[8][8];
    #pragma unroll
    for (int a_ = 0; a_ < 8; ++a_)
      #pragma unroll
      for (int b_ = 0; b_ < 8; ++b_) acc[a_][b_] = 0.f;

    for (int kc = 0; kc < 5; ++kc) {
      __syncthreads();
      for (int i = tid; i < 128 * 15; i += 256) {
        int mm = i / 15, kq = i - mm * 15;
        float4 v = *(const float4*)&emb[(size_t)tokid[mm] * EE + kc * 60 + kq * 4];
        As[kq*4+0][mm] = v.x; As[kq*4+1][mm] = v.y;
        As[kq*4+2][mm] = v.z; As[kq*4+3][mm] = v.w;
      }
      for (int i = tid; i < 128 * 15; i += 256) {
        int nn = i / 15, kq = i - nn * 15;
        float4 v = *(const float4*)&W_ih[(size_t)(nt*128+nn) * EE + kc * 60 + kq * 4];
        Ws[kq*4+0][nn] = v.x; Ws[kq*4+1][nn] = v.y;
        Ws[kq*4+2][nn] = v.z; Ws[kq*4+3][nn] = v.w;
      }
      __syncthreads();
      for (int kk = 0; kk < 60; ++kk) {
        float4 a0 = *(const float4*)&As[kk][ty*8];
        float4 a1 = *(const float4*)&As[kk][ty*8+4];
        float4 w0 = *(const float4*)&Ws[kk][tx*8];
        float4 w1 = *(const float4*)&Ws[kk][tx*8+4];
        float av[8] = {a0.x,a0.y,a0.z,a0.w,a1.x,a1.y,a1.z,a1.w};
        float wv8[8] = {w0.x,w0.y,w0.z,w0.w,w1.x,w1.y,w1.z,w1.w};
        #pragma unroll
        for (int im = 0; im < 8; ++im)
          #pragma unroll
          for (int in = 0; in < 8; ++in) acc[im][in] += av[im] * wv8[in];
      }
    }
    #pragma unroll
    for (int im = 0; im < 8; ++im) {
      int m = ty*8 + im;
      int n = nt*128 + tx*8;
      float4 o0, o1;
      o0.x = acc[im][0] + bias[n+0]; o0.y = acc[im][1] + bias[n+1];
      o0.z = acc[im][2] + bias[n+2]; o0.w = acc[im][3] + bias[n+3];
      o1.x = acc[im][4] + bias[n+4]; o1.y = acc[im][5] + bias[n+5];
      o1.z = acc[im][6] + bias[n+6]; o1.w = acc[im][7] + bias[n+7];
      float* dst = &xgc[(size_t)(dir*16384 + r*128 + m) * GG + n];
      *(float4*)dst = o0; *(float4*)(dst+4) = o1;
    }
  }
}

// ---------------- recurrence for one 64-step chunk: 128 independent blocks x 1024 thr ----------------
// Block = (dir, 4 batches). Thread tid = gate row (GEMM phase) and (cb=tid>>8, cj=tid&255) cell.
// h ping-pongs in LDS; W_hh streamed from L2 via k-major Wt (coalesced float4, lane = row).
// No cross-block communication: all sync is __syncthreads; chunk boundary = kernel boundary.
__global__ __launch_bounds__(1024) void rec_chunk_kernel(
    const float* __restrict__ xgc, const float* __restrict__ Wt,
    const int* __restrict__ lens,
    float* __restrict__ hst, float* __restrict__ cst,
    float* __restrict__ emisf, float* __restrict__ emisb,
    const float* __restrict__ W_out, const float* __restrict__ b_out, int ci)
{
  __shared__ __align__(16) float hring[2][4][HH];   // ping-pong h for 4 batches
  __shared__ float gbuf[GG * 5];                    // gates, stride-5 (odd) -> conflict-free
  __shared__ __align__(16) float Wo[KK][HH];        // W_out half for this dir

  const int tid = threadIdx.x;
  const int dir = blockIdx.x >> 6;
  const int b0  = (blockIdx.x & 63) * 4;
  const int cb  = tid >> 8, cj = tid & 255;
  float* emis = dir ? emisb : emisf;

  for (int i = tid; i < KK * (HH/4); i += 1024) {
    int k = i >> 6, q = i & 63;
    *(float4*)&Wo[k][q*4] = *(const float4*)&W_out[(size_t)k * (2*HH) + dir*HH + q*4];
  }

  // emission role: 576 threads = (eb<4, ek<9, es<16), 16-lane dot groups (tid = (eb*9+ek)*16+es)
  int eb = 0, ek = 0, es = 0;
  const bool edo = tid < 4 * KK * 16;
  if (edo) { int q = tid; eb = q / 144; q -= eb * 144; ek = q >> 4; es = q & 15; }
  const float ebias = (edo && dir == 0) ? b_out[ek] : 0.f;

  const int len_c = lens[b0 + cb];
  float h_reg, c_reg;
  if (ci == 0) { h_reg = 0.f; c_reg = 0.f; }
  else {
    h_reg = hst[((size_t)dir*BB + b0 + cb) * HH + cj];
    c_reg = cst[((size_t)dir*BB + b0 + cb) * HH + cj];
  }
  hring[0][cb][cj] = h_reg;
  __syncthreads();

  const float4* wbase = (const float4*)Wt + (size_t)dir * 65536 + tid;
  const float4* hb4   = (const float4*)&hring[0][0][0];    // viewed as [2][4][64] float4

  for (int sl = 0; sl < CHS; ++sl) {
    const int s = ci * CHS + sl;
    const int t = dir ? (TT - 1 - s) : s;
    const int cur = sl & 1, nxt = cur ^ 1;

    // ---- gate GEMM: acc[b] = xg + dot(W_hh[row], h_prev[b]) ----
    const float* xb = xgc + ((size_t)dir*(CHS*BB) + (size_t)sl*BB + b0) * GG + tid;
    float a0 = xb[0], a1 = xb[GG], a2 = xb[2*GG], a3 = xb[3*GG];
    const float4* hc = hb4 + cur * (4*64);
    #pragma unroll 2
    for (int k4 = 0; k4 < 64; ++k4) {
      float4 w  = wbase[(size_t)k4 * GG];       // coalesced: lanes = consecutive rows
      float4 h0 = hc[k4];                       // wave-uniform -> LDS broadcast
      float4 h1 = hc[64 + k4];
      float4 h2 = hc[128 + k4];
      float4 h3 = hc[192 + k4];
      a0 += w.x*h0.x; a0 += w.y*h0.y; a0 += w.z*h0.z; a0 += w.w*h0.w;
      a1 += w.x*h1.x; a1 += w.y*h1.y; a1 += w.z*h1.z; a1 += w.w*h1.w;
      a2 += w.x*h2.x; a2 += w.y*h2.y; a2 += w.z*h2.z; a2 += w.w*h2.w;
      a3 += w.x*h3.x; a3 += w.y*h3.y; a3 += w.z*h3.z; a3 += w.w*h3.w;
    }
    gbuf[tid*5+0] = a0; gbuf[tid*5+1] = a1; gbuf[tid*5+2] = a2; gbuf[tid*5+3] = a3;
    __syncthreads();

    // ---- cell update: thread (cb, cj) ----
    {
      float gi = gbuf[(0*256 + cj)*5 + cb];
      float gf = gbuf[(1*256 + cj)*5 + cb];
      float gg = gbuf[(2*256 + cj)*5 + cb];
      float go = gbuf[(3*256 + cj)*5 + cb];
      float si = 1.f / (1.f + expf(-gi));
      float sf = 1.f / (1.f + expf(-gf));
      float so = 1.f / (1.f + expf(-go));
      float cn = sf * c_reg + si * tanhf(gg);
      float hn = so * tanhf(cn);
      bool m = t < len_c;
      h_reg = m ? hn : h_reg;
      c_reg = m ? cn : c_reg;
      hring[nxt][cb][cj] = h_reg;
    }
    __syncthreads();

    // ---- fused emission for this timestep (h_new in hring[nxt]) ----
    if (edo) {
      float r = 0.f;
      #pragma unroll
      for (int i4 = 0; i4 < 4; ++i4) {
        // lane-consecutive float4 (es fastest) -> conflict-free
        float4 h4 = *(const float4*)&hring[nxt][eb][es*4 + i4*64];
        float4 w4 = *(const float4*)&Wo[ek][es*4 + i4*64];
        r += h4.x*w4.x + h4.y*w4.y + h4.z*w4.z + h4.w*w4.w;
      }
      r += __shfl_xor(r, 8); r += __shfl_xor(r, 4);
      r += __shfl_xor(r, 2); r += __shfl_xor(r, 1);
      if (es == 0)
        emis[((size_t)(b0 + eb) * TT + t) * KK + ek] = r + ebias;
    }
  }

  hst[((size_t)dir*BB + b0 + cb) * HH + cj] = h_reg;
  cst[((size_t)dir*BB + b0 + cb) * HH + cj] = c_reg;
}

// ---------------- CRF (identical numerics to rounds 1-4) ----------------
__global__ __launch_bounds__(64) void crf_kernel(
    const float* __restrict__ emis_f, const float* __restrict__ emis_b2,
    const int* __restrict__ labels, const int* __restrict__ lens,
    const float* __restrict__ start_trans, const float* __restrict__ end_trans,
    const float* __restrict__ trans,
    float* __restrict__ numden, float* __restrict__ outp)
{
  const int b = blockIdx.x;
  const int lane = threadIdx.x;
  __shared__ __align__(16) float em[TT * KK];
  __shared__ unsigned char hist[TT * KK];
  const float4* ef = (const float4*)(emis_f + (size_t)b * TT * KK);
  const float4* eb = (const float4*)(emis_b2 + (size_t)b * TT * KK);
  for (int i = lane; i < TT*KK/4; i += 64) {
    float4 a = ef[i], c = eb[i];
    float4 o; o.x = a.x+c.x; o.y = a.y+c.y; o.z = a.z+c.z; o.w = a.w+c.w;
    ((float4*)em)[i] = o;
  }
  const int len = lens[b];
  const int k = lane < KK ? lane : KK-1;
  float tc[KK];
  #pragma unroll
  for (int jj = 0; jj < KK; ++jj) tc[jj] = trans[jj*KK + k];
  __syncthreads();

  float nacc = 0.f;
  for (int t = lane; t < TT; t += 64) {
    int lt = labels[t*BB + b];
    if (t == 0) nacc += start_trans[lt] + em[lt];
    else if (t < len) nacc += trans[labels[(t-1)*BB + b]*KK + lt] + em[t*KK + lt];
  }
  if (lane == 0) nacc += end_trans[labels[(size_t)(len-1)*BB + b]];
  #pragma unroll
  for (int off = 32; off; off >>= 1) nacc += __shfl_down(nacc, off);

  float alpha[KK], score[KK];
  #pragma unroll
  for (int jj = 0; jj < KK; ++jj) {
    float v = start_trans[jj] + em[jj];
    alpha[jj] = v; score[jj] = v;
  }
  for (int t = 1; t < TT; ++t) {
    float av[KK]; float mx = -1e30f;
    #pragma unroll
    for (int jj = 0; jj < KK; ++jj) { av[jj] = alpha[jj] + tc[jj]; mx = fmaxf(mx, av[jj]); }
    float ssum = 0.f;
    #pragma unroll
    for (int jj = 0; jj < KK; ++jj) ssum += expf(av[jj] - mx);
    float e_tk = em[t*KK + k];
    float na = mx + logf(ssum) + e_tk;
    float best = -1e30f; int bj = 0;
    #pragma unroll
    for (int jj = 0; jj < KK; ++jj) {
      float sv = score[jj] + tc[jj];
      if (sv > best) { best = sv; bj = jj; }
    }
    float ns = best + e_tk;
    bool msk = t < len;
    na = msk ? na : alpha[k];
    ns = msk ? ns : score[k];
    if (lane < KK) hist[(t-1)*KK + lane] = (unsigned char)bj;
    #pragma unroll
    for (int jj = 0; jj < KK; ++jj) { alpha[jj] = __shfl(na, jj); score[jj] = __shfl(ns, jj); }
  }
  float dm = -1e30f;
  #pragma unroll
  for (int jj = 0; jj < KK; ++jj) dm = fmaxf(dm, alpha[jj] + end_trans[jj]);
  float dsum = 0.f;
  #pragma unroll
  for (int jj = 0; jj < KK; ++jj) dsum += expf(alpha[jj] + end_trans[jj] - dm);
  float denom = dm + logf(dsum);
  int bl_ = 0; float bs = -1e30f;
  #pragma unroll
  for (int jj = 0; jj < KK; ++jj) {
    float v = score[jj] + end_trans[jj];
    if (v > bs) { bs = v; bl_ = jj; }
  }
  if (lane == 0) numden[b] = nacc - denom;
  __syncthreads();
  if (lane == 0) {
    int tag = bl_;
    outp[1 + (size_t)(TT-1)*BB + b] = ((TT-1) < len) ? (float)bl_ : 0.f;
    for (int s = TT-2; s >= 0; --s) {
      tag = ((s+1) < len) ? (int)hist[s*KK + tag] : bl_;
      outp[1 + (size_t)s*BB + b] = (s < len) ? (float)tag : 0.f;
    }
  }
}

__global__ __launch_bounds__(256) void loss_reduce_kernel(
    const float* __restrict__ numden, float* __restrict__ out)
{
  __shared__ float sh[256];
  int tid = threadIdx.x;
  sh[tid] = numden[tid];
  __syncthreads();
  for (int s = 128; s > 0; s >>= 1) {
    if (tid < s) sh[tid] += sh[tid + s];
    __syncthreads();
  }
  if (tid == 0) out[0] = -sh[0];
}

extern "C" void kernel_launch(void* const* d_in, const int* in_sizes, int n_in,
                              void* d_out, int out_size, void* d_ws, size_t ws_size,
                              hipStream_t stream)
{
  const int*   ids    = (const int*)d_in[0];
  const int*   lens   = (const int*)d_in[1];
  const int*   labels = (const int*)d_in[2];
  const float* emb    = (const float*)d_in[3];
  const float* W_ih_f = (const float*)d_in[4];
  const float* W_hh_f = (const float*)d_in[5];
  const float* b_f    = (const float*)d_in[6];
  const float* W_ih_b = (const float*)d_in[7];
  const float* W_hh_b = (const float*)d_in[8];
  const float* b_b    = (const float*)d_in[9];
  const float* W_out  = (const float*)d_in[10];
  const float* b_out  = (const float*)d_in[11];
  const float* s_tr   = (const float*)d_in[12];
  const float* e_tr   = (const float*)d_in[13];
  const float* trans  = (const float*)d_in[14];
  float* out = (float*)d_out;

  float* ws = (float*)d_ws;
  float* xgc    = ws + OFF_XG;
  float* Wt     = ws + OFF_WT;
  float* hst    = ws + OFF_HS;
  float* cst    = ws + OFF_CS;
  float* emis_f = ws + OFF_EF;
  float* emis_b = ws + OFF_EB;
  float* numden = ws + OFF_ND;

  wtrans_kernel<<<128, 1024, 0, stream>>>(W_hh_f, W_hh_b, Wt);

  for (int ci = 0; ci < NCH; ++ci) {
    gemm_xg_kernel<<<256, 256, 0, stream>>>(ids, emb, W_ih_f, W_ih_b, b_f, b_b, xgc, ci);
    rec_chunk_kernel<<<128, 1024, 0, stream>>>(xgc, Wt, lens, hst, cst,
                                               emis_f, emis_b, W_out, b_out, ci);
  }

  crf_kernel<<<BB, 64, 0, stream>>>(emis_f, emis_b, labels, lens, s_tr, e_tr, trans, numden, out);
  loss_reduce_kernel<<<1, 256, 0, stream>>>(numden, out);
}